// Round 1
// baseline (441.219 us; speedup 1.0000x reference)
//
#include <hip/hip_runtime.h>

#define HIDDEN 768
#define NH 12
#define DH 64
#define BB 4
#define TT 2048
#define MTOT (BB * TT)  // 8192

typedef __bf16 bf16x8 __attribute__((ext_vector_type(8)));
typedef float f32x4 __attribute__((ext_vector_type(4)));

__device__ __forceinline__ unsigned short f2b(float f) {
    unsigned u = __builtin_bit_cast(unsigned, f);
    u += 0x7fffu + ((u >> 16) & 1u);  // round-to-nearest-even
    return (unsigned short)(u >> 16);
}

// ---------------- fp32 -> bf16 conversion ----------------
__global__ __launch_bounds__(256) void cvt_kernel(const float* __restrict__ in,
                                                  unsigned short* __restrict__ out,
                                                  int n8) {
    int i = blockIdx.x * 256 + threadIdx.x;
    if (i >= n8) return;
    const float4* p = (const float4*)in + (size_t)i * 2;
    float4 a = p[0], b = p[1];
    union { uint4 u; unsigned short s[8]; } t;
    t.s[0] = f2b(a.x); t.s[1] = f2b(a.y); t.s[2] = f2b(a.z); t.s[3] = f2b(a.w);
    t.s[4] = f2b(b.x); t.s[5] = f2b(b.y); t.s[6] = f2b(b.z); t.s[7] = f2b(b.w);
    *((uint4*)out + i) = t.u;
}

// ---------------- GEMM: C[M,N] = A[M,K] @ B[N,K]^T (bf16 in, fp32 acc) ----------------
// 128x128 block tile, 4 waves in 2x2, each wave 64x64 (4x4 MFMA tiles), BK=64.
// LDS fragment-major layout [kq][row][8]: lane reads its 16B A/B fragment contiguously.
template <int OUTF>
__global__ __launch_bounds__(256) void gemm_bt(const unsigned short* __restrict__ A,
                                               const unsigned short* __restrict__ Bm,
                                               float* __restrict__ Cf,
                                               unsigned short* __restrict__ Cb,
                                               int M, int N, int K) {
    __shared__ __align__(16) unsigned short Al[8][128][8];
    __shared__ __align__(16) unsigned short Bl[8][128][8];
    const int tid = threadIdx.x;
    const int lane = tid & 63;
    const int wave = tid >> 6;
    const int quad = lane >> 4;
    const int l16 = lane & 15;
    const int mBase = blockIdx.x * 128;
    const int nBase = blockIdx.y * 128;
    const int mw = (wave >> 1) * 64;
    const int nw = (wave & 1) * 64;

    f32x4 acc[4][4];
#pragma unroll
    for (int mt = 0; mt < 4; ++mt)
#pragma unroll
        for (int nt = 0; nt < 4; ++nt) acc[mt][nt] = (f32x4){0.f, 0.f, 0.f, 0.f};

    const int nkb = K >> 6;
    for (int kb = 0; kb < nkb; ++kb) {
        const int k0 = kb << 6;
#pragma unroll
        for (int p = 0; p < 4; ++p) {
            int idx = p * 256 + tid;
            int m = idx >> 3, c = idx & 7;
            *(uint4*)&Al[c][m][0] = *(const uint4*)&A[(size_t)(mBase + m) * K + k0 + c * 8];
            *(uint4*)&Bl[c][m][0] = *(const uint4*)&Bm[(size_t)(nBase + m) * K + k0 + c * 8];
        }
        __syncthreads();
#pragma unroll
        for (int ks = 0; ks < 2; ++ks) {
            bf16x8 af[4], bf[4];
#pragma unroll
            for (int t = 0; t < 4; ++t) {
                af[t] = *(const bf16x8*)&Al[ks * 4 + quad][mw + t * 16 + l16][0];
                bf[t] = *(const bf16x8*)&Bl[ks * 4 + quad][nw + t * 16 + l16][0];
            }
#pragma unroll
            for (int mt = 0; mt < 4; ++mt)
#pragma unroll
                for (int nt = 0; nt < 4; ++nt)
                    acc[mt][nt] = __builtin_amdgcn_mfma_f32_16x16x32_bf16(
                        af[mt], bf[nt], acc[mt][nt], 0, 0, 0);
        }
        __syncthreads();
    }

#pragma unroll
    for (int mt = 0; mt < 4; ++mt)
#pragma unroll
        for (int nt = 0; nt < 4; ++nt)
#pragma unroll
            for (int r = 0; r < 4; ++r) {
                int row = mBase + mw + mt * 16 + quad * 4 + r;
                int col = nBase + nw + nt * 16 + l16;
                float v = acc[mt][nt][r];
                if (OUTF)
                    Cf[(size_t)row * N + col] = v;
                else
                    Cb[(size_t)row * N + col] = f2b(v);
            }
}

// ---------------- Flash attention ----------------
// Block: one (b,h) x 128 q-rows. 4 waves, each owns 32 q-rows (2 m-tiles).
// Loop over 32 K-tiles of 64 keys: S = Q K^T (MFMA), online softmax, P->LDS->A-layout, PV MFMA.
__global__ __launch_bounds__(256) void attn_kernel(const unsigned short* __restrict__ Qg,
                                                   const unsigned short* __restrict__ Kg,
                                                   const unsigned short* __restrict__ Vg,
                                                   unsigned short* __restrict__ Ctx) {
    __shared__ __align__(16) unsigned short Kl[8][64][8];  // [d/8][key][8] : K[key][d]
    __shared__ __align__(16) unsigned short Vl[8][64][8];  // [key/8][d][8] : V[key][d] transposed
    __shared__ __align__(16) unsigned short Pl[8][128][8]; // [key/8][q][8] : P[q][key]
    const int tid = threadIdx.x;
    const int lane = tid & 63;
    const int wave = tid >> 6;
    const int quad = lane >> 4;
    const int l16 = lane & 15;
    const int qt = blockIdx.x;  // 0..15
    const int bh = blockIdx.y;  // 0..47
    const int b = bh / NH, h = bh % NH;
    const int qrow0 = b * TT + qt * 128;
    const int col0 = h * DH;
    const float sc2 = 0.18033688011112042f;  // log2(e) / sqrt(64)

    // Preload Q fragments (stay in registers for the whole kernel)
    bf16x8 qf[2][2];
#pragma unroll
    for (int mt = 0; mt < 2; ++mt)
#pragma unroll
        for (int ks = 0; ks < 2; ++ks)
            qf[mt][ks] = *(const bf16x8*)&Qg[(size_t)(qrow0 + wave * 32 + mt * 16 + l16) * HIDDEN +
                                             col0 + ks * 32 + quad * 8];

    f32x4 o[2][4];
    float mi[2][4], li[2][4];
#pragma unroll
    for (int mt = 0; mt < 2; ++mt) {
#pragma unroll
        for (int nt = 0; nt < 4; ++nt) o[mt][nt] = (f32x4){0.f, 0.f, 0.f, 0.f};
#pragma unroll
        for (int r = 0; r < 4; ++r) { mi[mt][r] = -3.0e38f; li[mt][r] = 0.f; }
    }

    for (int kt = 0; kt < TT / 64; ++kt) {
        const int krow0 = b * TT + kt * 64;
        __syncthreads();  // protect Kl/Vl/Pl reuse from previous iteration's readers
#pragma unroll
        for (int p = 0; p < 2; ++p) {
            int idx = p * 256 + tid;
            int key = idx >> 3, c = idx & 7;
            *(uint4*)&Kl[c][key][0] =
                *(const uint4*)&Kg[(size_t)(krow0 + key) * HIDDEN + col0 + c * 8];
            union { uint4 u; unsigned short s[8]; } t;
            t.u = *(const uint4*)&Vg[(size_t)(krow0 + key) * HIDDEN + col0 + c * 8];
#pragma unroll
            for (int e = 0; e < 8; ++e) Vl[key >> 3][c * 8 + e][key & 7] = t.s[e];
        }
        __syncthreads();

        // S = Q K^T  (fp32 accum)
        f32x4 s[2][4];
#pragma unroll
        for (int mt = 0; mt < 2; ++mt)
#pragma unroll
            for (int nt = 0; nt < 4; ++nt) s[mt][nt] = (f32x4){0.f, 0.f, 0.f, 0.f};
#pragma unroll
        for (int ks = 0; ks < 2; ++ks) {
            bf16x8 kf[4];
#pragma unroll
            for (int nt = 0; nt < 4; ++nt)
                kf[nt] = *(const bf16x8*)&Kl[ks * 4 + quad][nt * 16 + l16][0];
#pragma unroll
            for (int mt = 0; mt < 2; ++mt)
#pragma unroll
                for (int nt = 0; nt < 4; ++nt)
                    s[mt][nt] = __builtin_amdgcn_mfma_f32_16x16x32_bf16(qf[mt][ks], kf[nt],
                                                                        s[mt][nt], 0, 0, 0);
        }

        // Online softmax in log2 domain (t = s * log2e/8). Row lives in one 16-lane quad.
#pragma unroll
        for (int mt = 0; mt < 2; ++mt)
#pragma unroll
            for (int r = 0; r < 4; ++r) {
                float rm = s[mt][0][r];
#pragma unroll
                for (int nt = 1; nt < 4; ++nt) rm = fmaxf(rm, s[mt][nt][r]);
                rm *= sc2;
                rm = fmaxf(rm, __shfl_xor(rm, 1));
                rm = fmaxf(rm, __shfl_xor(rm, 2));
                rm = fmaxf(rm, __shfl_xor(rm, 4));
                rm = fmaxf(rm, __shfl_xor(rm, 8));
                float mnew = fmaxf(mi[mt][r], rm);
                float alpha = __builtin_amdgcn_exp2f(mi[mt][r] - mnew);
                mi[mt][r] = mnew;
                float rs = 0.f;
#pragma unroll
                for (int nt = 0; nt < 4; ++nt) {
                    float pv = __builtin_amdgcn_exp2f(s[mt][nt][r] * sc2 - mnew);
                    s[mt][nt][r] = pv;
                    rs += pv;
                }
                rs += __shfl_xor(rs, 1);
                rs += __shfl_xor(rs, 2);
                rs += __shfl_xor(rs, 4);
                rs += __shfl_xor(rs, 8);
                li[mt][r] = li[mt][r] * alpha + rs;
#pragma unroll
                for (int nt = 0; nt < 4; ++nt) o[mt][nt][r] *= alpha;
            }

        // P (C-layout regs) -> LDS (A-layout)
#pragma unroll
        for (int mt = 0; mt < 2; ++mt)
#pragma unroll
            for (int nt = 0; nt < 4; ++nt)
#pragma unroll
                for (int r = 0; r < 4; ++r)
                    Pl[nt * 2 + (l16 >> 3)][wave * 32 + mt * 16 + quad * 4 + r][l16 & 7] =
                        f2b(s[mt][nt][r]);
        __syncthreads();

        // O += P V
#pragma unroll
        for (int ks = 0; ks < 2; ++ks) {
            bf16x8 pf[2], vf[4];
#pragma unroll
            for (int mt = 0; mt < 2; ++mt)
                pf[mt] = *(const bf16x8*)&Pl[ks * 4 + quad][wave * 32 + mt * 16 + l16][0];
#pragma unroll
            for (int nt = 0; nt < 4; ++nt)
                vf[nt] = *(const bf16x8*)&Vl[ks * 4 + quad][nt * 16 + l16][0];
#pragma unroll
            for (int mt = 0; mt < 2; ++mt)
#pragma unroll
                for (int nt = 0; nt < 4; ++nt)
                    o[mt][nt] = __builtin_amdgcn_mfma_f32_16x16x32_bf16(pf[mt], vf[nt],
                                                                        o[mt][nt], 0, 0, 0);
        }
    }

    // Epilogue: O /= l, write ctx (bf16) at [row][h*64+d]
#pragma unroll
    for (int mt = 0; mt < 2; ++mt)
#pragma unroll
        for (int r = 0; r < 4; ++r) {
            float inv = 1.0f / li[mt][r];
            int row = qrow0 + wave * 32 + mt * 16 + quad * 4 + r;
#pragma unroll
            for (int nt = 0; nt < 4; ++nt) {
                int col = col0 + nt * 16 + l16;
                Ctx[(size_t)row * HIDDEN + col] = f2b(o[mt][nt][r] * inv);
            }
        }
}

// ---------------- launch ----------------
extern "C" void kernel_launch(void* const* d_in, const int* in_sizes, int n_in,
                              void* d_out, int out_size, void* d_ws, size_t ws_size,
                              hipStream_t stream) {
    const float* x = (const float*)d_in[0];
    const float* wq = (const float*)d_in[1];
    const float* wk = (const float*)d_in[2];
    const float* wv = (const float*)d_in[3];
    const float* wo = (const float*)d_in[4];
    float* out = (float*)d_out;

    const size_t NX = (size_t)MTOT * HIDDEN;    // 6291456
    const size_t NW = (size_t)HIDDEN * HIDDEN;  // 589824
    unsigned short* ws = (unsigned short*)d_ws;
    unsigned short* xb = ws;
    unsigned short* wqb = xb + NX;
    unsigned short* wkb = wqb + NW;
    unsigned short* wvb = wkb + NW;
    unsigned short* wob = wvb + NW;
    unsigned short* qb = wob + NW;
    unsigned short* kb = qb + NX;
    unsigned short* vb = kb + NX;
    unsigned short* cb = vb + NX;

    cvt_kernel<<<(int)(NX / 8 / 256), 256, 0, stream>>>(x, xb, (int)(NX / 8));
    cvt_kernel<<<(int)(NW / 8 / 256), 256, 0, stream>>>(wq, wqb, (int)(NW / 8));
    cvt_kernel<<<(int)(NW / 8 / 256), 256, 0, stream>>>(wk, wkb, (int)(NW / 8));
    cvt_kernel<<<(int)(NW / 8 / 256), 256, 0, stream>>>(wv, wvb, (int)(NW / 8));
    cvt_kernel<<<(int)(NW / 8 / 256), 256, 0, stream>>>(wo, wob, (int)(NW / 8));

    dim3 gg(MTOT / 128, HIDDEN / 128);
    gemm_bt<0><<<gg, 256, 0, stream>>>(xb, wqb, nullptr, qb, MTOT, HIDDEN, HIDDEN);
    gemm_bt<0><<<gg, 256, 0, stream>>>(xb, wkb, nullptr, kb, MTOT, HIDDEN, HIDDEN);
    gemm_bt<0><<<gg, 256, 0, stream>>>(xb, wvb, nullptr, vb, MTOT, HIDDEN, HIDDEN);

    attn_kernel<<<dim3(TT / 128, BB * NH), 256, 0, stream>>>(qb, kb, vb, cb);

    gemm_bt<1><<<gg, 256, 0, stream>>>(cb, wob, out, nullptr, MTOT, HIDDEN, HIDDEN);
}

// Round 2
// 312.292 us; speedup vs baseline: 1.4128x; 1.4128x over previous
//
#include <hip/hip_runtime.h>

#define HIDDEN 768
#define NH 12
#define DH 64
#define BB 4
#define TT 2048
#define MTOT (BB * TT)  // 8192

typedef __bf16 bf16x8 __attribute__((ext_vector_type(8)));
typedef short s16x8 __attribute__((ext_vector_type(8)));
typedef float f32x4 __attribute__((ext_vector_type(4)));

__device__ __forceinline__ unsigned short f2b(float f) {
    unsigned u = __builtin_bit_cast(unsigned, f);
    u += 0x7fffu + ((u >> 16) & 1u);  // RNE
    return (unsigned short)(u >> 16);
}

typedef const __attribute__((address_space(1))) unsigned int* gas_ptr;
typedef __attribute__((address_space(3))) unsigned int* las_ptr;
__device__ __forceinline__ void gload16(const void* g, void* l) {
    // LDS dest is wave-uniform base; HW scatters lane i at base + i*16.
    __builtin_amdgcn_global_load_lds((gas_ptr)(uintptr_t)g, (las_ptr)(uintptr_t)l, 16, 0, 0);
}

// ---------------- fp32 -> bf16 conversion (with fused scale) ----------------
__global__ __launch_bounds__(256) void cvt_kernel(const float* __restrict__ in,
                                                  unsigned short* __restrict__ out,
                                                  int n8, float scale) {
    int i = blockIdx.x * 256 + threadIdx.x;
    if (i >= n8) return;
    const float4* p = (const float4*)in + (size_t)i * 2;
    float4 a = p[0], b = p[1];
    union { uint4 u; unsigned short s[8]; } t;
    t.s[0] = f2b(a.x * scale); t.s[1] = f2b(a.y * scale);
    t.s[2] = f2b(a.z * scale); t.s[3] = f2b(a.w * scale);
    t.s[4] = f2b(b.x * scale); t.s[5] = f2b(b.y * scale);
    t.s[6] = f2b(b.z * scale); t.s[7] = f2b(b.w * scale);
    *((uint4*)out + i) = t.u;
}

// ---------------- GEMM: C[M,N] = A[M,K] @ B[N,K]^T ----------------
// 64x128 block tile, 4 waves 2x2 (each 32x64), BK=64, global_load_lds(16) staging.
template <int OUTF>
__global__ __launch_bounds__(256) void gemm_bt(const unsigned short* __restrict__ A,
                                               const unsigned short* __restrict__ Bm,
                                               float* __restrict__ Cf,
                                               unsigned short* __restrict__ Cb,
                                               int M, int N, int K) {
    __shared__ __align__(16) unsigned short Al[8][64][8];
    __shared__ __align__(16) unsigned short Bl[8][128][8];
    const int tid = threadIdx.x;
    const int lane = tid & 63;
    const int wave = tid >> 6;
    const int quad = lane >> 4;
    const int l16 = lane & 15;
    const int mBase = blockIdx.x * 64;
    const int nBase = blockIdx.y * 128;
    const int mw = (wave >> 1) * 32;
    const int nw = (wave & 1) * 64;

    f32x4 acc[2][4];
#pragma unroll
    for (int mt = 0; mt < 2; ++mt)
#pragma unroll
        for (int nt = 0; nt < 4; ++nt) acc[mt][nt] = (f32x4){0.f, 0.f, 0.f, 0.f};

    const int nkb = K >> 6;
    for (int kb = 0; kb < nkb; ++kb) {
        const int k0 = kb << 6;
        // A: 512 chunks of 16B; wave w covers c = {2w, 2w+1}, lane = row
#pragma unroll
        for (int i = 0; i < 2; ++i) {
            int c = wave * 2 + i;
            gload16(&A[(size_t)(mBase + lane) * K + k0 + c * 8], &Al[c][0][0]);
        }
        // B: 1024 chunks; wave w covers c = {2w, 2w+1} x n0 = {0, 64}
#pragma unroll
        for (int j = 0; j < 4; ++j) {
            int c = wave * 2 + (j >> 1);
            int n0 = (j & 1) * 64;
            gload16(&Bm[(size_t)(nBase + n0 + lane) * K + k0 + c * 8], &Bl[c][n0][0]);
        }
        __syncthreads();
#pragma unroll
        for (int ks = 0; ks < 2; ++ks) {
            bf16x8 af[2], bf[4];
#pragma unroll
            for (int mt = 0; mt < 2; ++mt)
                af[mt] = *(const bf16x8*)&Al[ks * 4 + quad][mw + mt * 16 + l16][0];
#pragma unroll
            for (int nt = 0; nt < 4; ++nt)
                bf[nt] = *(const bf16x8*)&Bl[ks * 4 + quad][nw + nt * 16 + l16][0];
#pragma unroll
            for (int mt = 0; mt < 2; ++mt)
#pragma unroll
                for (int nt = 0; nt < 4; ++nt)
                    acc[mt][nt] = __builtin_amdgcn_mfma_f32_16x16x32_bf16(
                        af[mt], bf[nt], acc[mt][nt], 0, 0, 0);
        }
        __syncthreads();
    }

#pragma unroll
    for (int mt = 0; mt < 2; ++mt)
#pragma unroll
        for (int nt = 0; nt < 4; ++nt)
#pragma unroll
            for (int r = 0; r < 4; ++r) {
                int row = mBase + mw + mt * 16 + quad * 4 + r;
                int col = nBase + nw + nt * 16 + l16;
                float v = acc[mt][nt][r];
                if (OUTF)
                    Cf[(size_t)row * N + col] = v;
                else
                    Cb[(size_t)row * N + col] = f2b(v);
            }
}

// ---------------- V transpose: [8192][768] -> [768][8192] ----------------
__global__ __launch_bounds__(256) void vt_kernel(const unsigned short* __restrict__ in,
                                                 unsigned short* __restrict__ out) {
    __shared__ unsigned short T[64][73];  // odd-ish stride: conflict-free both ways
    const int tid = threadIdx.x;
    const int r0 = blockIdx.x * 64;  // M dim
    const int c0 = blockIdx.y * 64;  // hidden dim
#pragma unroll
    for (int p = 0; p < 2; ++p) {
        int idx = p * 256 + tid;
        int r = idx >> 3, c = idx & 7;
        union { uint4 u; unsigned short s[8]; } t;
        t.u = *(const uint4*)&in[(size_t)(r0 + r) * HIDDEN + c0 + c * 8];
#pragma unroll
        for (int e = 0; e < 8; ++e) T[r][c * 8 + e] = t.s[e];
    }
    __syncthreads();
#pragma unroll
    for (int p = 0; p < 2; ++p) {
        int idx = p * 256 + tid;
        int cc = idx >> 3, rc = idx & 7;
        union { uint4 u; unsigned short s[8]; } t;
#pragma unroll
        for (int e = 0; e < 8; ++e) t.s[e] = T[rc * 8 + e][cc];
        *(uint4*)&out[(size_t)(c0 + cc) * MTOT + r0 + rc * 8] = t.u;
    }
}

// ---------------- Flash attention (no-max softmax; row sums via MFMA) ----------------
// Block: one (b,h) x 128 q-rows; 4 waves x 32 q-rows. V pre-transposed globally.
// All LDS row-major stride 72 (pad +8): staging writes / b128 reads at BW floor.
__global__ __launch_bounds__(256) void attn_kernel(const unsigned short* __restrict__ Qg,
                                                   const unsigned short* __restrict__ Kg,
                                                   const unsigned short* __restrict__ VTg,
                                                   unsigned short* __restrict__ Ctx) {
    __shared__ __align__(16) unsigned short Kl[64][72];   // [key][d]
    __shared__ __align__(16) unsigned short Vl[64][72];   // [d][key]  (from V^T)
    __shared__ __align__(16) unsigned short Pl[128][72];  // [q][key]
    const int tid = threadIdx.x;
    const int lane = tid & 63;
    const int wave = tid >> 6;
    const int quad = lane >> 4;
    const int l16 = lane & 15;
    const int qt = blockIdx.x;  // 0..15
    const int bh = blockIdx.y;  // 0..47
    const int b = bh / NH, h = bh % NH;
    const int qrow0 = b * TT + qt * 128;
    const int col0 = h * DH;

    // Q fragments (log2e/8 pre-folded into w_q): resident all kernel
    bf16x8 qf[2][2];
#pragma unroll
    for (int mt = 0; mt < 2; ++mt)
#pragma unroll
        for (int ks = 0; ks < 2; ++ks)
            qf[mt][ks] = *(const bf16x8*)&Qg[(size_t)(qrow0 + wave * 32 + mt * 16 + l16) * HIDDEN +
                                             col0 + ks * 32 + quad * 8];

    s16x8 osv;
#pragma unroll
    for (int e = 0; e < 8; ++e) osv[e] = 0x3F80;  // bf16 1.0
    const bf16x8 ones = __builtin_bit_cast(bf16x8, osv);

    f32x4 o[2][4];
    f32x4 lacc[2];
#pragma unroll
    for (int mt = 0; mt < 2; ++mt) {
        lacc[mt] = (f32x4){0.f, 0.f, 0.f, 0.f};
#pragma unroll
        for (int nt = 0; nt < 4; ++nt) o[mt][nt] = (f32x4){0.f, 0.f, 0.f, 0.f};
    }

    for (int kt = 0; kt < TT / 64; ++kt) {
        const int krow0 = b * TT + kt * 64;
        __syncthreads();  // all waves done reading Kl/Vl/Pl of previous tile
#pragma unroll
        for (int p = 0; p < 2; ++p) {
            int idx = p * 256 + tid;
            int a = idx >> 3, c = idx & 7;
            *(uint4*)&Kl[a][c * 8] =
                *(const uint4*)&Kg[(size_t)(krow0 + a) * HIDDEN + col0 + c * 8];
            *(uint4*)&Vl[a][c * 8] =
                *(const uint4*)&VTg[(size_t)(col0 + a) * MTOT + krow0 + c * 8];
        }
        __syncthreads();

        // S = Q' K^T  (already in log2 units)
        f32x4 s[2][4];
#pragma unroll
        for (int mt = 0; mt < 2; ++mt)
#pragma unroll
            for (int nt = 0; nt < 4; ++nt) s[mt][nt] = (f32x4){0.f, 0.f, 0.f, 0.f};
#pragma unroll
        for (int ks = 0; ks < 2; ++ks) {
            bf16x8 kf[4];
#pragma unroll
            for (int nt = 0; nt < 4; ++nt)
                kf[nt] = *(const bf16x8*)&Kl[nt * 16 + l16][ks * 32 + quad * 8];
#pragma unroll
            for (int mt = 0; mt < 2; ++mt)
#pragma unroll
                for (int nt = 0; nt < 4; ++nt)
                    s[mt][nt] = __builtin_amdgcn_mfma_f32_16x16x32_bf16(qf[mt][ks], kf[nt],
                                                                        s[mt][nt], 0, 0, 0);
        }

        // P = exp2(S), truncated to bf16 (row-sum via MFMA uses the SAME truncated
        // values, so quantization bias cancels in the normalization).
#pragma unroll
        for (int mt = 0; mt < 2; ++mt) {
            int row0 = wave * 32 + mt * 16 + quad * 4;
#pragma unroll
            for (int nt = 0; nt < 4; ++nt) {
                int col = nt * 16 + l16;
#pragma unroll
                for (int r = 0; r < 4; ++r) {
                    float pv = __builtin_amdgcn_exp2f(s[mt][nt][r]);
                    Pl[row0 + r][col] =
                        (unsigned short)(__builtin_bit_cast(unsigned, pv) >> 16);
                }
            }
        }
        __syncthreads();

        // O += P V ; l += P . 1
#pragma unroll
        for (int ks = 0; ks < 2; ++ks) {
            bf16x8 pf[2], vf[4];
#pragma unroll
            for (int mt = 0; mt < 2; ++mt)
                pf[mt] = *(const bf16x8*)&Pl[wave * 32 + mt * 16 + l16][ks * 32 + quad * 8];
#pragma unroll
            for (int nt = 0; nt < 4; ++nt)
                vf[nt] = *(const bf16x8*)&Vl[nt * 16 + l16][ks * 32 + quad * 8];
#pragma unroll
            for (int mt = 0; mt < 2; ++mt)
                lacc[mt] = __builtin_amdgcn_mfma_f32_16x16x32_bf16(pf[mt], ones, lacc[mt], 0, 0, 0);
#pragma unroll
            for (int mt = 0; mt < 2; ++mt)
#pragma unroll
                for (int nt = 0; nt < 4; ++nt)
                    o[mt][nt] = __builtin_amdgcn_mfma_f32_16x16x32_bf16(pf[mt], vf[nt],
                                                                        o[mt][nt], 0, 0, 0);
        }
    }

    // Epilogue: normalize by row sums (already in C-layout, no shuffles)
#pragma unroll
    for (int mt = 0; mt < 2; ++mt)
#pragma unroll
        for (int r = 0; r < 4; ++r) {
            float inv = __builtin_amdgcn_rcpf(lacc[mt][r]);
            int row = qrow0 + wave * 32 + mt * 16 + quad * 4 + r;
#pragma unroll
            for (int nt = 0; nt < 4; ++nt)
                Ctx[(size_t)row * HIDDEN + col0 + nt * 16 + l16] = f2b(o[mt][nt][r] * inv);
        }
}

// ---------------- launch ----------------
extern "C" void kernel_launch(void* const* d_in, const int* in_sizes, int n_in,
                              void* d_out, int out_size, void* d_ws, size_t ws_size,
                              hipStream_t stream) {
    const float* x = (const float*)d_in[0];
    const float* wq = (const float*)d_in[1];
    const float* wk = (const float*)d_in[2];
    const float* wv = (const float*)d_in[3];
    const float* wo = (const float*)d_in[4];
    float* out = (float*)d_out;

    const size_t NX = (size_t)MTOT * HIDDEN;
    const size_t NW = (size_t)HIDDEN * HIDDEN;
    unsigned short* ws = (unsigned short*)d_ws;
    unsigned short* xb = ws;
    unsigned short* wqb = xb + NX;
    unsigned short* wkb = wqb + NW;
    unsigned short* wvb = wkb + NW;
    unsigned short* wob = wvb + NW;
    unsigned short* qb = wob + NW;
    unsigned short* kb = qb + NX;
    unsigned short* vb = kb + NX;
    unsigned short* vtb = vb + NX;
    unsigned short* cb = vb;  // alias: vb dead after vt_kernel

    const float SC2 = 0.18033688011112042f;  // log2(e)/sqrt(64)

    cvt_kernel<<<(int)(NX / 8 / 256), 256, 0, stream>>>(x, xb, (int)(NX / 8), 1.0f);
    cvt_kernel<<<(int)(NW / 8 / 256), 256, 0, stream>>>(wq, wqb, (int)(NW / 8), SC2);
    cvt_kernel<<<(int)(NW / 8 / 256), 256, 0, stream>>>(wk, wkb, (int)(NW / 8), 1.0f);
    cvt_kernel<<<(int)(NW / 8 / 256), 256, 0, stream>>>(wv, wvb, (int)(NW / 8), 1.0f);
    cvt_kernel<<<(int)(NW / 8 / 256), 256, 0, stream>>>(wo, wob, (int)(NW / 8), 1.0f);

    dim3 gg(MTOT / 64, HIDDEN / 128);
    gemm_bt<0><<<gg, 256, 0, stream>>>(xb, wqb, nullptr, qb, MTOT, HIDDEN, HIDDEN);
    gemm_bt<0><<<gg, 256, 0, stream>>>(xb, wkb, nullptr, kb, MTOT, HIDDEN, HIDDEN);
    gemm_bt<0><<<gg, 256, 0, stream>>>(xb, wvb, nullptr, vb, MTOT, HIDDEN, HIDDEN);

    vt_kernel<<<dim3(MTOT / 64, HIDDEN / 64), 256, 0, stream>>>(vb, vtb);

    attn_kernel<<<dim3(TT / 128, BB * NH), 256, 0, stream>>>(qb, kb, vtb, cb);

    gemm_bt<1><<<gg, 256, 0, stream>>>(cb, wob, out, nullptr, MTOT, HIDDEN, HIDDEN);
}